// Round 1
// baseline (751.764 us; speedup 1.0000x reference)
//
#include <hip/hip_runtime.h>
#include <math.h>

#define D_MODEL 1024
#define NUM_SEGS 64
#define CT 64                         // tokens per wave-chunk
#define TOTAL_TOKENS 131072
#define MAXC (TOTAL_TOKENS / CT + NUM_SEGS)   // 2112: upper bound on chunk count
#define WAVES_PER_BLOCK 4

// ---------------------------------------------------------------------------
// Pass 1: per wave-chunk online softmax-weighted accumulation.
// Each wave owns one chunk of <=CT tokens, all inside one segment.
// Lane l holds row dims {l*4 + k*256 .. +3} for k=0..3 (coalesced float4 loads).
// ---------------------------------------------------------------------------
__global__ __launch_bounds__(256) void seg_pool_pass1(
    const float* __restrict__ x, const int* __restrict__ cu,
    const float* __restrict__ W, const float* __restrict__ bias_p,
    float* __restrict__ m_arr, float* __restrict__ l_arr,
    float* __restrict__ o_arr)
{
    __shared__ int s_cu[NUM_SEGS + 1];   // token offsets
    __shared__ int s_cuc[NUM_SEGS + 1];  // chunk-count prefix sum

    const int tid = threadIdx.x;
    if (tid <= NUM_SEGS) s_cu[tid] = cu[tid];
    __syncthreads();
    if (tid == 0) {
        int acc = 0;
        s_cuc[0] = 0;
        for (int s = 0; s < NUM_SEGS; ++s) {
            acc += (s_cu[s + 1] - s_cu[s] + CT - 1) / CT;
            s_cuc[s + 1] = acc;
        }
    }
    __syncthreads();

    const int wave = tid >> 6;
    const int lane = tid & 63;
    const int chunk = blockIdx.x * WAVES_PER_BLOCK + wave;
    const int total_chunks = s_cuc[NUM_SEGS];
    if (chunk >= total_chunks) return;

    // binary search: seg with s_cuc[seg] <= chunk < s_cuc[seg+1]
    int lo = 0, hi = NUM_SEGS;
    while (hi - lo > 1) {
        int mid = (lo + hi) >> 1;
        if (s_cuc[mid] <= chunk) lo = mid; else hi = mid;
    }
    const int seg = lo;
    const int t0 = s_cu[seg] + (chunk - s_cuc[seg]) * CT;
    const int t1 = min(t0 + CT, s_cu[seg + 1]);

    // W fragment + bias (cached once per wave)
    float4 w4[4];
#pragma unroll
    for (int k = 0; k < 4; ++k)
        w4[k] = *(const float4*)(W + k * 256 + lane * 4);
    const float bias = bias_p[0];

    float m = -INFINITY;
    float lsum = 0.0f;
    float4 o[4];
#pragma unroll
    for (int k = 0; k < 4; ++k) o[k] = make_float4(0.f, 0.f, 0.f, 0.f);

    for (int t = t0; t < t1; ++t) {
        const float* row = x + (size_t)t * D_MODEL;
        float4 v[4];
#pragma unroll
        for (int k = 0; k < 4; ++k)
            v[k] = *(const float4*)(row + k * 256 + lane * 4);

        float dot = 0.0f;
#pragma unroll
        for (int k = 0; k < 4; ++k) {
            dot += v[k].x * w4[k].x;
            dot += v[k].y * w4[k].y;
            dot += v[k].z * w4[k].z;
            dot += v[k].w * w4[k].w;
        }
        // full 64-lane butterfly reduce -> dot identical on all lanes
#pragma unroll
        for (int off = 32; off > 0; off >>= 1)
            dot += __shfl_xor(dot, off, 64);

        const float sc = dot + bias;
        const float mnew = fmaxf(m, sc);
        const float scale = __expf(m - mnew);   // first iter: exp(-inf)=0
        const float p = __expf(sc - mnew);
        lsum = lsum * scale + p;
#pragma unroll
        for (int k = 0; k < 4; ++k) {
            o[k].x = o[k].x * scale + p * v[k].x;
            o[k].y = o[k].y * scale + p * v[k].y;
            o[k].z = o[k].z * scale + p * v[k].z;
            o[k].w = o[k].w * scale + p * v[k].w;
        }
        m = mnew;
    }

    if (lane == 0) { m_arr[chunk] = m; l_arr[chunk] = lsum; }
    float* op = o_arr + (size_t)chunk * D_MODEL;
#pragma unroll
    for (int k = 0; k < 4; ++k)
        *(float4*)(op + k * 256 + lane * 4) = o[k];
}

// ---------------------------------------------------------------------------
// Pass 2: one block per segment; merge chunk partials.
// out[seg][d] = sum_c e^{m_c-m*} o_c[d] / sum_c e^{m_c-m*} l_c
// ---------------------------------------------------------------------------
__global__ __launch_bounds__(256) void seg_pool_pass2(
    const int* __restrict__ cu,
    const float* __restrict__ m_arr, const float* __restrict__ l_arr,
    const float* __restrict__ o_arr, float* __restrict__ out)
{
    __shared__ int s_cu[NUM_SEGS + 1];
    __shared__ int s_cuc[NUM_SEGS + 1];

    const int tid = threadIdx.x;
    if (tid <= NUM_SEGS) s_cu[tid] = cu[tid];
    __syncthreads();
    if (tid == 0) {
        int acc = 0;
        s_cuc[0] = 0;
        for (int s = 0; s < NUM_SEGS; ++s) {
            acc += (s_cu[s + 1] - s_cu[s] + CT - 1) / CT;
            s_cuc[s + 1] = acc;
        }
    }
    __syncthreads();

    const int seg = blockIdx.x;
    const int c0 = s_cuc[seg], c1 = s_cuc[seg + 1];

    float mstar = -INFINITY;
    for (int c = c0; c < c1; ++c) mstar = fmaxf(mstar, m_arr[c]);

    float4 acc = make_float4(0.f, 0.f, 0.f, 0.f);
    float lstar = 0.0f;
    for (int c = c0; c < c1; ++c) {
        const float sc = __expf(m_arr[c] - mstar);
        lstar += sc * l_arr[c];
        const float4 oc = *(const float4*)(o_arr + (size_t)c * D_MODEL + tid * 4);
        acc.x += sc * oc.x;
        acc.y += sc * oc.y;
        acc.z += sc * oc.z;
        acc.w += sc * oc.w;
    }
    const float inv = 1.0f / lstar;
    acc.x *= inv; acc.y *= inv; acc.z *= inv; acc.w *= inv;
    *(float4*)(out + (size_t)seg * D_MODEL + tid * 4) = acc;
}

extern "C" void kernel_launch(void* const* d_in, const int* in_sizes, int n_in,
                              void* d_out, int out_size, void* d_ws, size_t ws_size,
                              hipStream_t stream) {
    const float* x  = (const float*)d_in[0];
    const int*   cu = (const int*)d_in[1];
    const float* W  = (const float*)d_in[2];
    const float* b  = (const float*)d_in[3];
    float* out = (float*)d_out;

    // workspace layout: m[MAXC] | l[MAXC] | o[MAXC][1024]
    float* m_arr = (float*)d_ws;
    float* l_arr = m_arr + MAXC;
    float* o_arr = l_arr + MAXC;   // 2*MAXC*4 = 16896 B, 16B-aligned

    const int blocks1 = (MAXC + WAVES_PER_BLOCK - 1) / WAVES_PER_BLOCK;  // 528
    seg_pool_pass1<<<dim3(blocks1), dim3(256), 0, stream>>>(
        x, cu, W, b, m_arr, l_arr, o_arr);
    seg_pool_pass2<<<dim3(NUM_SEGS), dim3(256), 0, stream>>>(
        cu, m_arr, l_arr, o_arr, out);
}